// Round 7
// baseline (223.332 us; speedup 1.0000x reference)
//
#include <hip/hip_runtime.h>
#include <hip/hip_fp16.h>
#include <math.h>

// GCN: out = softmax( S·relu((S·h)W1 + b1) · W2 + b2 ),  S = in-edge sum + self-loop.
// Round 17: REVERT to round-15 structure (R16's fixed-stride CSR inflated traffic
// and regressed) + ONE delta: degree-sorted node permutation for both gathers.
// Waves then hold equal-degree nodes -> wave-max dmax ≈ d, killing the ~37% of
// row loads that went to clamp-duplicates and idle-node slots. perm is pure
// scheduling: per-node CSR sum order unchanged -> bit-identical results.
// Degree histogram folded into fill_b (LDS); dscan + dscatter are tiny launches;
// dscatter pre-aggregates per-block in LDS so no hot-bin global atomic serialization.

constexpr int N = 100000;
constexpr int E = 1200000;
constexpr int D = 64;    // input dim
constexpr int H = 128;   // hidden
constexpr int C = 40;    // classes
constexpr int NBUCK2 = 98;                      // buckets of 1024 dst nodes
constexpr int EBLK   = 2048;                    // edges per histo/append block
constexpr int NHB    = (E + EBLK - 1) / EBLK;   // 586 edge blocks
constexpr int DB     = 128;                     // degree bins

typedef _Float16 f16x8 __attribute__((ext_vector_type(8)));
typedef float    f32x4 __attribute__((ext_vector_type(4)));

// ---- W1 -> fragment-ordered fp16 ----
__global__ __launch_bounds__(256) void prep_w1(const float* __restrict__ W1,
                                               f16x8* __restrict__ wfrag) {
    int e = blockIdx.x * 256 + threadIdx.x;   // 4 blocks x 256 = 1024
    int l = e & 63, cf = e >> 6;              // cf = ct*2+f
    int f = cf & 1, ct = cf >> 1;
    int kbase = f * 32 + (l >> 4) * 8;
    int c = ct * 16 + (l & 15);
    f16x8 v;
#pragma unroll
    for (int r = 0; r < 8; ++r)
        v[r] = (_Float16)W1[(kbase + r) * H + c];
    wfrag[e] = v;
}

// ---- histo (98 buckets) + grid-stride h->fp16 convert + dcnt zero ----
__global__ __launch_bounds__(256) void histo_conv(const int2* __restrict__ edges,
                                                  int* __restrict__ partial,
                                                  const float2* __restrict__ hf,
                                                  __half2* __restrict__ HH,
                                                  int* __restrict__ dcnt) {
    __shared__ int cnt[NBUCK2];
    if (threadIdx.x < NBUCK2) cnt[threadIdx.x] = 0;
    if (blockIdx.x == 1 && threadIdx.x < DB) dcnt[threadIdx.x] = 0;
    for (int i = blockIdx.x * 256 + threadIdx.x; i < N * 32; i += NHB * 256) {
        float2 p = hf[i];
        HH[i] = __floats2half2_rn(p.x, p.y);
    }
    __syncthreads();
    int base = blockIdx.x * EBLK + threadIdx.x * 8;
#pragma unroll
    for (int i = 0; i < 8; ++i) {
        int e = base + i;
        if (e < E) atomicAdd(&cnt[edges[e].y >> 10], 1);
    }
    __syncthreads();
    if (threadIdx.x < NBUCK2)
        partial[blockIdx.x * NBUCK2 + threadIdx.x] = cnt[threadIdx.x];
}

// ---- per-bucket column scan of partial: obase[b][blk], btot[b] ----
__global__ __launch_bounds__(1024) void scan_pb(const int* __restrict__ partial,
                                                int* __restrict__ obase,
                                                int* __restrict__ btot) {
    __shared__ int s[1024];
    int b = blockIdx.x, t = threadIdx.x;
    int v = (t < NHB) ? partial[t * NBUCK2 + b] : 0;
    s[t] = v;
    __syncthreads();
    for (int off = 1; off < 1024; off <<= 1) {
        int x = (t >= off) ? s[t - off] : 0;
        __syncthreads();
        s[t] += x;
        __syncthreads();
    }
    if (t < NHB) obase[b * NHB + t] = s[t] - v;   // exclusive within bucket
    if (t == 1023) btot[b] = s[1023];
}

// ---- exclusive scan of bucket totals -> bstart[0..NBUCK2] ----
__global__ __launch_bounds__(128) void scan_bt(const int* __restrict__ btot,
                                               int* __restrict__ bstart) {
    __shared__ int s[128];
    int t = threadIdx.x;
    int v = (t < NBUCK2) ? btot[t] : 0;
    s[t] = v;
    __syncthreads();
    for (int off = 1; off < 128; off <<= 1) {
        int x = (t >= off) ? s[t - off] : 0;
        __syncthreads();
        s[t] += x;
        __syncthreads();
    }
    if (t < NBUCK2) bstart[t] = s[t] - v;
    if (t == NBUCK2 - 1) bstart[NBUCK2] = s[t];   // = E
}

// ---- append: deterministic positions, LDS cursors seeded from scanned bases ----
__global__ __launch_bounds__(256) void append_b(const int2* __restrict__ edges,
                                                const int* __restrict__ bstart,
                                                const int* __restrict__ obase,
                                                int* __restrict__ staging) {
    __shared__ int cur[NBUCK2];
    int blk = blockIdx.x;
    if (threadIdx.x < NBUCK2)
        cur[threadIdx.x] = bstart[threadIdx.x] + obase[threadIdx.x * NHB + blk];
    __syncthreads();
    int base = blk * EBLK + threadIdx.x * 8;
#pragma unroll
    for (int i = 0; i < 8; ++i) {
        int e = base + i;
        if (e < E) {
            int2 ed = edges[e];
            int b = ed.y >> 10;
            int p = atomicAdd(&cur[b], 1);               // LDS atomic
            staging[p] = (ed.x << 10) | (ed.y & 1023);   // src:17b | dst_local:10b
        }
    }
}

// ---- per-bucket: count + scan -> rd(row_start,deg), scatter csr; + degree histo ----
__global__ __launch_bounds__(1024) void fill_b(const int* __restrict__ staging,
                                               const int* __restrict__ bstart,
                                               int2* __restrict__ rd,
                                               int* __restrict__ csr,
                                               int* __restrict__ dcnt) {
    __shared__ int cnt[1024], s[1024], cur[1024];
    __shared__ int dh[DB];
    int b = blockIdx.x, t = threadIdx.x;
    cnt[t] = 0;
    if (t < DB) dh[t] = 0;
    __syncthreads();
    int lo = bstart[b], hi = bstart[b + 1];
    for (int i = lo + t; i < hi; i += 1024)
        atomicAdd(&cnt[staging[i] & 1023], 1);
    __syncthreads();
    int v = cnt[t];
    int node = (b << 10) + t;
    if (node < N) atomicAdd(&dh[min(v, DB - 1)], 1);   // LDS degree histo
    s[t] = v;
    __syncthreads();
    for (int off = 1; off < 1024; off <<= 1) {
        int x = (t >= off) ? s[t - off] : 0;
        __syncthreads();
        s[t] += x;
        __syncthreads();
    }
    int ex = s[t] - v;
    cur[t] = ex;
    if (node < N) rd[node] = make_int2(lo + ex, v);
    __syncthreads();
    for (int i = lo + t; i < hi; i += 1024) {
        int w = staging[i];
        int p = atomicAdd(&cur[w & 1023], 1);
        csr[lo + p] = w >> 10;
    }
    if (t < DB && dh[t]) atomicAdd(&dcnt[t], dh[t]);   // merge (scan barriers fence dh)
}

// ---- exclusive scan of degree bins -> dstart; reset dcnt for scatter cursors ----
__global__ __launch_bounds__(DB) void dscan(int* __restrict__ dcnt,
                                            int* __restrict__ dstart) {
    __shared__ int s[DB];
    int t = threadIdx.x;
    int v = dcnt[t];
    s[t] = v;
    __syncthreads();
    for (int off = 1; off < DB; off <<= 1) {
        int x = (t >= off) ? s[t - off] : 0;
        __syncthreads();
        s[t] += x;
        __syncthreads();
    }
    dstart[t] = s[t] - v;
    dcnt[t] = 0;
}

// ---- scatter nodes into degree-sorted perm; per-block LDS aggregation so global
//      atomics are one-per-bin-per-block (no hot-bin serialization) ----
__global__ __launch_bounds__(256) void dscatter(const int2* __restrict__ rd,
                                                const int* __restrict__ dstart,
                                                int* __restrict__ dcnt,
                                                int* __restrict__ perm) {
    __shared__ int lh[DB], lbase[DB], lcur[DB];
    int t = threadIdx.x;
    if (t < DB) { lh[t] = 0; lcur[t] = 0; }
    __syncthreads();
    int node = blockIdx.x * 256 + t;
    int d = -1;
    if (node < N) {
        d = min(rd[node].y, DB - 1);
        atomicAdd(&lh[d], 1);
    }
    __syncthreads();
    if (t < DB && lh[t]) lbase[t] = atomicAdd(&dcnt[t], lh[t]);
    __syncthreads();
    if (node < N) {
        int p = atomicAdd(&lcur[d], 1);
        perm[dstart[d] + lbase[d] + p] = node;
    }
}

// ---- FUSED layer 1 (R15 structure + perm): gather (4 nodes/wave, 16 lanes/node,
//      batch-8) -> fp16 LDS a_h[16][72], then MFMA 16x16x32_f16, scatter rows ----
__global__ __launch_bounds__(256) void fused1(const __half2* __restrict__ HH,
                                              const int* __restrict__ csr,
                                              const int2* __restrict__ rd,
                                              const int* __restrict__ perm,
                                              const f16x8* __restrict__ wfrag,
                                              const float* __restrict__ b1,
                                              __half* __restrict__ XH) {
    __shared__ _Float16 a_h[16 * 72] __attribute__((aligned(16)));
    __shared__ int pn[16];
    // ---- gather phase ----
    int nl = threadIdx.x >> 4;                 // node-local 0..15
    int fl = threadIdx.x & 15;
    int node = perm[blockIdx.x * 16 + nl];
    if (fl == 0) pn[nl] = node;
    const float2* H4 = (const float2*)HH;      // row = 16 float2 = 128 B
    int2 rdv = rd[node];
    int rs = rdv.x, d = rdv.y;
    if (d == 0) rs = 0;                        // safe dummy window
    int cl = (d > 0) ? d - 1 : 0;
    int dmax = d;                              // wave-uniform; ~d after deg-sort
    dmax = max(dmax, __shfl_xor(dmax, 16));
    dmax = max(dmax, __shfl_xor(dmax, 32));
    float a0, a1, a2, a3;
    {   // self-loop init
        float2 raw = H4[node * 16 + fl];
        const __half2* hp = (const __half2*)&raw;
        float2 v0 = __half22float2(hp[0]), v1 = __half22float2(hp[1]);
        a0 = v0.x; a1 = v0.y; a2 = v1.x; a3 = v1.y;
    }
    for (int j0 = 0; j0 < dmax; j0 += 8) {     // 8 rows in flight per node
        int k[8]; float w[8];
#pragma unroll
        for (int t = 0; t < 8; ++t) {
            int jj = j0 + t;
            bool ok = jj < d;
            w[t] = ok ? 1.f : 0.f;
            k[t] = csr[rs + (ok ? jj : cl)];
        }
#pragma unroll
        for (int t = 0; t < 8; ++t) {
            float2 raw = H4[k[t] * 16 + fl];
            const __half2* hp = (const __half2*)&raw;
            float2 v0 = __half22float2(hp[0]), v1 = __half22float2(hp[1]);
            a0 = fmaf(w[t], v0.x, a0); a1 = fmaf(w[t], v0.y, a1);
            a2 = fmaf(w[t], v1.x, a2); a3 = fmaf(w[t], v1.y, a3);
        }
    }
    *(__half2*)&a_h[nl * 72 + fl * 4]     = __floats2half2_rn(a0, a1);
    *(__half2*)&a_h[nl * 72 + fl * 4 + 2] = __floats2half2_rn(a2, a3);
    __syncthreads();
    // ---- MFMA phase: wave wv -> col tiles t0=2wv, t1=2wv+1 ----
    int wv = threadIdx.x >> 6;
    int l  = threadIdx.x & 63;
    int lg = l >> 4, lr = l & 15;
    f16x8 aA0 = *(const f16x8*)&a_h[lr * 72 + 0 * 32 + lg * 8];
    f16x8 aA1 = *(const f16x8*)&a_h[lr * 72 + 1 * 32 + lg * 8];
    int t0 = wv * 2, t1 = wv * 2 + 1;
    f16x8 b00 = wfrag[(t0 * 2 + 0) * 64 + l];
    f16x8 b01 = wfrag[(t0 * 2 + 1) * 64 + l];
    f16x8 b10 = wfrag[(t1 * 2 + 0) * 64 + l];
    f16x8 b11 = wfrag[(t1 * 2 + 1) * 64 + l];
    f32x4 acc0 = {0.f, 0.f, 0.f, 0.f}, acc1 = {0.f, 0.f, 0.f, 0.f};
    acc0 = __builtin_amdgcn_mfma_f32_16x16x32_f16(aA0, b00, acc0, 0, 0, 0);
    acc0 = __builtin_amdgcn_mfma_f32_16x16x32_f16(aA1, b01, acc0, 0, 0, 0);
    acc1 = __builtin_amdgcn_mfma_f32_16x16x32_f16(aA0, b10, acc1, 0, 0, 0);
    acc1 = __builtin_amdgcn_mfma_f32_16x16x32_f16(aA1, b11, acc1, 0, 0, 0);
    // ---- epilogue: D col = lane&15, row = (lane>>4)*4 + r; rows scatter via pn ----
    int c0 = t0 * 16 + lr, c1 = t1 * 16 + lr;
    float bias0 = b1[c0], bias1 = b1[c1];
#pragma unroll
    for (int r = 0; r < 4; ++r) {
        int rown = pn[lg * 4 + r];
        XH[rown * H + c0] = __float2half_rn(fmaxf(acc0[r] + bias0, 0.f));
        XH[rown * H + c1] = __float2half_rn(fmaxf(acc1[r] + bias1, 0.f));
    }
}

// ---- ZH = fp16(XH @ W2), row stride 64 halves, cols 40..63 zero-filled ----
constexpr int XS = 132;
__global__ __launch_bounds__(256) void gemm2(const __half* __restrict__ XH,
                                             const float* __restrict__ W2,
                                             __half* __restrict__ ZH) {
    __shared__ float w_s[H * C];        // 20 KB
    __shared__ float x_s[64 * XS];      // 33.8 KB
    int row0 = blockIdx.x * 64;
    {
        const float4* src = (const float4*)W2;
        float4* dst = (float4*)w_s;
#pragma unroll
        for (int i = 0; i < 5; ++i)
            dst[threadIdx.x + i * 256] = src[threadIdx.x + i * 256];
    }
    {   // stage XH (fp16) -> x_s (fp32): 64 rows x 16 chunks of 8 halves
#pragma unroll
        for (int i = 0; i < 4; ++i) {
            int idx = threadIdx.x + i * 256;   // 1024 chunks
            int r = idx >> 4;
            int q = idx & 15;
            int grow = row0 + r;
            if (grow >= N) grow = N - 1;
            float4 raw = *(const float4*)&XH[grow * H + q * 8];
            __half2* hp = (__half2*)&raw;
            float2 f0 = __half22float2(hp[0]), f1 = __half22float2(hp[1]);
            float2 f2 = __half22float2(hp[2]), f3 = __half22float2(hp[3]);
            float* dst = &x_s[r * XS + q * 8];
            dst[0] = f0.x; dst[1] = f0.y; dst[2] = f1.x; dst[3] = f1.y;
            dst[4] = f2.x; dst[5] = f2.y; dst[6] = f3.x; dst[7] = f3.y;
        }
    }
    __syncthreads();

    int tc   = threadIdx.x & 7;         // cols tc*5 .. tc*5+4
    int trow = threadIdx.x >> 3;        // rows trow*2, trow*2+1
    float acc[2][5] = {};
#pragma unroll 4
    for (int k = 0; k < H; ++k) {
        float b[5];
#pragma unroll
        for (int j = 0; j < 5; ++j) b[j] = w_s[k * C + tc * 5 + j];
        float a0 = x_s[(trow * 2) * XS + k];
        float a1 = x_s[(trow * 2 + 1) * XS + k];
#pragma unroll
        for (int j = 0; j < 5; ++j) {
            acc[0][j] = fmaf(a0, b[j], acc[0][j]);
            acc[1][j] = fmaf(a1, b[j], acc[1][j]);
        }
    }
#pragma unroll
    for (int i = 0; i < 2; ++i) {
        int row = row0 + trow * 2 + i;
        if (row < N) {
#pragma unroll
            for (int j = 0; j < 5; ++j)
                ZH[row * 64 + tc * 5 + j] = __float2half_rn(acc[i][j]);
#pragma unroll
            for (int j = 0; j < 3; ++j)          // pad cols 40..63
                ZH[row * 64 + 40 + tc * 3 + j] = __half(0.f);
        }
    }
}

// ---- out[node] = softmax(Z[node] + sum Z[src] + b2): R15 structure + perm ----
__global__ __launch_bounds__(256) void gather2_softmax(const __half2* __restrict__ ZH,
                                                       const int* __restrict__ csr,
                                                       const int2* __restrict__ rd,
                                                       const int* __restrict__ perm,
                                                       const float* __restrict__ b2,
                                                       float4* __restrict__ out) {
    int node = perm[blockIdx.x * 16 + (threadIdx.x >> 4)];
    int fl = threadIdx.x & 15;
    const float2* Z4 = (const float2*)ZH;     // row = 16 float2 = 128 B (padded)
    int2 rdv = rd[node];
    int rs = rdv.x, d = rdv.y;
    if (d == 0) rs = 0;
    int cl = (d > 0) ? d - 1 : 0;
    int dmax = d;
    dmax = max(dmax, __shfl_xor(dmax, 16));
    dmax = max(dmax, __shfl_xor(dmax, 32));
    float a0, a1, a2, a3;
    {   // self-loop init
        float2 raw = Z4[node * 16 + fl];
        const __half2* hp = (const __half2*)&raw;
        float2 v0 = __half22float2(hp[0]), v1 = __half22float2(hp[1]);
        a0 = v0.x; a1 = v0.y; a2 = v1.x; a3 = v1.y;
    }
    for (int j0 = 0; j0 < dmax; j0 += 8) {
        int k[8]; float w[8];
#pragma unroll
        for (int t = 0; t < 8; ++t) {
            int jj = j0 + t;
            bool ok = jj < d;
            w[t] = ok ? 1.f : 0.f;
            k[t] = csr[rs + (ok ? jj : cl)];
        }
#pragma unroll
        for (int t = 0; t < 8; ++t) {
            float2 raw = Z4[k[t] * 16 + fl];
            const __half2* hp = (const __half2*)&raw;
            float2 v0 = __half22float2(hp[0]), v1 = __half22float2(hp[1]);
            a0 = fmaf(w[t], v0.x, a0); a1 = fmaf(w[t], v0.y, a1);
            a2 = fmaf(w[t], v1.x, a2); a3 = fmaf(w[t], v1.y, a3);
        }
    }
    // softmax over the 40 real cols (lanes fl<10, cols 4fl..4fl+3)
    const float4* b4 = (const float4*)b2;
    bool real = fl < 10;
    float4 bb = b4[real ? fl : 9];
    float v0 = real ? a0 + bb.x : -INFINITY;
    float v1 = real ? a1 + bb.y : -INFINITY;
    float v2 = real ? a2 + bb.z : -INFINITY;
    float v3 = real ? a3 + bb.w : -INFINITY;
    float m = fmaxf(fmaxf(v0, v1), fmaxf(v2, v3));
#pragma unroll
    for (int off = 1; off < 16; off <<= 1) m = fmaxf(m, __shfl_xor(m, off));
    float e0 = __expf(v0 - m), e1 = __expf(v1 - m);   // -inf lanes -> exp = 0
    float e2 = __expf(v2 - m), e3 = __expf(v3 - m);
    float s = (e0 + e1) + (e2 + e3);
#pragma unroll
    for (int off = 1; off < 16; off <<= 1) s += __shfl_xor(s, off);
    float inv = 1.f / s;
    if (real)
        out[node * 10 + fl] = make_float4(e0 * inv, e1 * inv, e2 * inv, e3 * inv);
}

extern "C" void kernel_launch(void* const* d_in, const int* in_sizes, int n_in,
                              void* d_out, int out_size, void* d_ws, size_t ws_size,
                              hipStream_t stream) {
    const float* h   = (const float*)d_in[0];   // N*D
    const int*   adj = (const int*)  d_in[1];   // E*2
    const float* W1  = (const float*)d_in[2];   // D*H
    const float* b1  = (const float*)d_in[3];   // H
    const float* W2  = (const float*)d_in[4];   // H*C
    const float* b2  = (const float*)d_in[5];   // C
    float* out = (float*)d_out;                 // N*C fp32

    // workspace, NO aliasing:
    //   w1frag 16KB | HH N*64 fp16 | XH N*128 fp16 | ZH N*64 fp16 | ints
    f16x8*  w1frag = (f16x8*)d_ws;                       // 1024 x 16 B
    __half* HH = (__half*)((char*)d_ws + 16384);         // N*64 fp16
    __half* XH = HH + (size_t)N * 64;                    // N*128 fp16
    __half* ZH = XH + (size_t)N * H;                     // N*64 fp16
    int* partial   = (int*)(ZH + (size_t)N * 64);        // NHB*NBUCK2
    int* obase     = partial + NHB * NBUCK2;             // NBUCK2*NHB
    int* btot      = obase + NBUCK2 * NHB;               // 128
    int* bstart    = btot + 128;                         // NBUCK2+1 (pad 128)
    int* staging   = bstart + 128;                       // E
    int* csr       = staging + E;                        // E
    int2* rd       = (int2*)(csr + E);                   // N (row_start, deg)
    int* dcnt      = (int*)(rd + N);                     // DB
    int* dstart    = dcnt + DB;                          // DB
    int* perm      = dstart + DB;                        // N

    prep_w1   <<<4, 256, 0, stream>>>(W1, w1frag);
    histo_conv<<<NHB, 256, 0, stream>>>((const int2*)adj, partial,
                                        (const float2*)h, (__half2*)HH, dcnt);
    scan_pb   <<<NBUCK2, 1024, 0, stream>>>(partial, obase, btot);
    scan_bt   <<<1, 128, 0, stream>>>(btot, bstart);
    append_b  <<<NHB, 256, 0, stream>>>((const int2*)adj, bstart, obase, staging);
    fill_b    <<<NBUCK2, 1024, 0, stream>>>(staging, bstart, rd, csr, dcnt);
    dscan     <<<1, DB, 0, stream>>>(dcnt, dstart);
    dscatter  <<<(N + 255) / 256, 256, 0, stream>>>(rd, dstart, dcnt, perm);

    fused1         <<<N / 16, 256, 0, stream>>>((const __half2*)HH, csr, rd, perm,
                                                w1frag, b1, XH);
    gemm2          <<<(N + 63) / 64, 256, 0, stream>>>(XH, W2, ZH);
    gather2_softmax<<<N / 16, 256, 0, stream>>>((const __half2*)ZH, csr, rd, perm,
                                                b2, (float4*)out);
}

// Round 8
// 189.546 us; speedup vs baseline: 1.1782x; 1.1782x over previous
//
#include <hip/hip_runtime.h>
#include <hip/hip_fp16.h>
#include <math.h>

// GCN: out = softmax( S·relu((S·h)W1 + b1) · W2 + b2 ),  S = in-edge sum + self-loop.
// Round 18: R15 baseline (best: 210.6us; R16/R17 gather restructures both regressed)
// + two deltas that do NOT touch the gather structure:
//  (1) gemm2 -> MFMA 16x16x32_f16 (W2 pre-packed frag-order padded to 48 cols; XH
//      staged raw fp16, stride 136 halves = 2-way-conflict-free; 12 MFMA/wave;
//      LDS 53.8KB->17KB). Cols 48..63 of ZH never consumed unmasked -> not stored.
//  (2) launches 9->7: prep_w1/prep_w2 folded into histo_conv blocks 0..6; scan_bt
//      deleted (append_b/fill_b recompute the 98-entry bucket scan locally in LDS).

constexpr int N = 100000;
constexpr int E = 1200000;
constexpr int D = 64;    // input dim
constexpr int H = 128;   // hidden
constexpr int C = 40;    // classes
constexpr int NBUCK2 = 98;                      // buckets of 1024 dst nodes
constexpr int EBLK   = 2048;                    // edges per histo/append block
constexpr int NHB    = (E + EBLK - 1) / EBLK;   // 586 edge blocks

typedef _Float16 f16x8 __attribute__((ext_vector_type(8)));
typedef float    f32x4 __attribute__((ext_vector_type(4)));

// ---- histo (98 buckets) + h->fp16 convert + W1/W2 fragment packs (blocks 0..6) ----
__global__ __launch_bounds__(256) void histo_conv(const int2* __restrict__ edges,
                                                  int* __restrict__ partial,
                                                  const float2* __restrict__ hf,
                                                  __half2* __restrict__ HH,
                                                  const float* __restrict__ W1,
                                                  const float* __restrict__ W2,
                                                  f16x8* __restrict__ w1frag,
                                                  f16x8* __restrict__ w2frag) {
    __shared__ int cnt[NBUCK2];
    if (threadIdx.x < NBUCK2) cnt[threadIdx.x] = 0;
    if (blockIdx.x < 4) {                       // pack W1 -> 1024 frags
        int e = blockIdx.x * 256 + threadIdx.x;
        int l = e & 63, cf = e >> 6;            // cf = ct*2+f
        int f = cf & 1, ct = cf >> 1;
        int kbase = f * 32 + (l >> 4) * 8;
        int c = ct * 16 + (l & 15);
        f16x8 v;
#pragma unroll
        for (int r = 0; r < 8; ++r)
            v[r] = (_Float16)W1[(kbase + r) * H + c];
        w1frag[e] = v;
    } else if (blockIdx.x < 7) {                // pack W2 -> 768 frags (48-col pad)
        int e = (blockIdx.x - 4) * 256 + threadIdx.x;
        int l = e & 63, cf = e >> 6;            // cf = ct*4+kc
        int kc = cf & 3, ct = cf >> 2;
        int kbase = kc * 32 + (l >> 4) * 8;
        int c = ct * 16 + (l & 15);
        f16x8 v;
#pragma unroll
        for (int r = 0; r < 8; ++r)
            v[r] = (c < C) ? (_Float16)W2[(kbase + r) * C + c] : (_Float16)0.f;
        w2frag[e] = v;
    }
    for (int i = blockIdx.x * 256 + threadIdx.x; i < N * 32; i += NHB * 256) {
        float2 p = hf[i];
        HH[i] = __floats2half2_rn(p.x, p.y);
    }
    __syncthreads();
    int base = blockIdx.x * EBLK + threadIdx.x * 8;
#pragma unroll
    for (int i = 0; i < 8; ++i) {
        int e = base + i;
        if (e < E) atomicAdd(&cnt[edges[e].y >> 10], 1);
    }
    __syncthreads();
    if (threadIdx.x < NBUCK2)
        partial[blockIdx.x * NBUCK2 + threadIdx.x] = cnt[threadIdx.x];
}

// ---- per-bucket column scan of partial: obase[b][blk], btot[b] ----
__global__ __launch_bounds__(1024) void scan_pb(const int* __restrict__ partial,
                                                int* __restrict__ obase,
                                                int* __restrict__ btot) {
    __shared__ int s[1024];
    int b = blockIdx.x, t = threadIdx.x;
    int v = (t < NHB) ? partial[t * NBUCK2 + b] : 0;
    s[t] = v;
    __syncthreads();
    for (int off = 1; off < 1024; off <<= 1) {
        int x = (t >= off) ? s[t - off] : 0;
        __syncthreads();
        s[t] += x;
        __syncthreads();
    }
    if (t < NHB) obase[b * NHB + t] = s[t] - v;   // exclusive within bucket
    if (t == 1023) btot[b] = s[1023];
}

// ---- append: LDS cursors = local-scan(btot) + obase; deterministic positions ----
__global__ __launch_bounds__(256) void append_b(const int2* __restrict__ edges,
                                                const int* __restrict__ btot,
                                                const int* __restrict__ obase,
                                                int* __restrict__ staging) {
    __shared__ int bs[128];
    __shared__ int cur[NBUCK2];
    int t = threadIdx.x, blk = blockIdx.x;
    if (t < 128) bs[t] = (t < NBUCK2) ? btot[t] : 0;
    __syncthreads();
    for (int off = 1; off < 128; off <<= 1) {     // inclusive scan (128 wide)
        int x = (t < 128 && t >= off) ? bs[t - off] : 0;
        __syncthreads();
        if (t < 128) bs[t] += x;
        __syncthreads();
    }
    if (t < NBUCK2) cur[t] = bs[t] - btot[t] + obase[t * NHB + blk];
    __syncthreads();
    int base = blk * EBLK + t * 8;
#pragma unroll
    for (int i = 0; i < 8; ++i) {
        int e = base + i;
        if (e < E) {
            int2 ed = edges[e];
            int b = ed.y >> 10;
            int p = atomicAdd(&cur[b], 1);               // LDS atomic
            staging[p] = (ed.x << 10) | (ed.y & 1023);   // src:17b | dst_local:10b
        }
    }
}

// ---- per-bucket: local-scan(btot) -> window, count + scan -> rd, scatter csr ----
__global__ __launch_bounds__(1024) void fill_b(const int* __restrict__ staging,
                                               const int* __restrict__ btot,
                                               int2* __restrict__ rd,
                                               int* __restrict__ csr) {
    __shared__ int bs[128];
    __shared__ int cnt[1024], s[1024], cur[1024];
    int b = blockIdx.x, t = threadIdx.x;
    cnt[t] = 0;
    if (t < 128) bs[t] = (t < NBUCK2) ? btot[t] : 0;
    __syncthreads();
    for (int off = 1; off < 128; off <<= 1) {     // inclusive scan (128 wide)
        int x = (t < 128 && t >= off) ? bs[t - off] : 0;
        __syncthreads();
        if (t < 128) bs[t] += x;
        __syncthreads();
    }
    int hi = bs[b];
    int lo = hi - btot[b];
    __syncthreads();
    for (int i = lo + t; i < hi; i += 1024)
        atomicAdd(&cnt[staging[i] & 1023], 1);
    __syncthreads();
    int v = cnt[t];
    s[t] = v;
    __syncthreads();
    for (int off = 1; off < 1024; off <<= 1) {
        int x = (t >= off) ? s[t - off] : 0;
        __syncthreads();
        s[t] += x;
        __syncthreads();
    }
    int ex = s[t] - v;
    cur[t] = ex;
    int node = (b << 10) + t;
    if (node < N) rd[node] = make_int2(lo + ex, v);
    __syncthreads();
    for (int i = lo + t; i < hi; i += 1024) {
        int w = staging[i];
        int p = atomicAdd(&cur[w & 1023], 1);
        csr[lo + p] = w >> 10;
    }
}

// ---- FUSED layer 1 (R15, unchanged): gather (4 nodes/wave, 16 lanes/node,
//      batch-8) -> fp16 LDS a_h[16][72], then MFMA 16x16x32_f16 ----
__global__ __launch_bounds__(256) void fused1(const __half2* __restrict__ HH,
                                              const int* __restrict__ csr,
                                              const int2* __restrict__ rd,
                                              const f16x8* __restrict__ wfrag,
                                              const float* __restrict__ b1,
                                              __half* __restrict__ XH) {
    __shared__ _Float16 a_h[16 * 72] __attribute__((aligned(16)));
    int nl = threadIdx.x >> 4;                 // node-local 0..15
    int fl = threadIdx.x & 15;
    int node = blockIdx.x * 16 + nl;
    const float2* H4 = (const float2*)HH;      // row = 16 float2 = 128 B
    int2 rdv = rd[node];
    int rs = rdv.x, d = rdv.y;
    if (d == 0) rs = 0;                        // safe dummy window
    int cl = (d > 0) ? d - 1 : 0;
    int dmax = d;                              // wave-uniform loop bound
    dmax = max(dmax, __shfl_xor(dmax, 16));
    dmax = max(dmax, __shfl_xor(dmax, 32));
    float a0, a1, a2, a3;
    {   // self-loop init
        float2 raw = H4[node * 16 + fl];
        const __half2* hp = (const __half2*)&raw;
        float2 v0 = __half22float2(hp[0]), v1 = __half22float2(hp[1]);
        a0 = v0.x; a1 = v0.y; a2 = v1.x; a3 = v1.y;
    }
    for (int j0 = 0; j0 < dmax; j0 += 8) {     // 8 rows in flight per node
        int k[8]; float w[8];
#pragma unroll
        for (int t = 0; t < 8; ++t) {
            int jj = j0 + t;
            bool ok = jj < d;
            w[t] = ok ? 1.f : 0.f;
            k[t] = csr[rs + (ok ? jj : cl)];
        }
#pragma unroll
        for (int t = 0; t < 8; ++t) {
            float2 raw = H4[k[t] * 16 + fl];
            const __half2* hp = (const __half2*)&raw;
            float2 v0 = __half22float2(hp[0]), v1 = __half22float2(hp[1]);
            a0 = fmaf(w[t], v0.x, a0); a1 = fmaf(w[t], v0.y, a1);
            a2 = fmaf(w[t], v1.x, a2); a3 = fmaf(w[t], v1.y, a3);
        }
    }
    *(__half2*)&a_h[nl * 72 + fl * 4]     = __floats2half2_rn(a0, a1);
    *(__half2*)&a_h[nl * 72 + fl * 4 + 2] = __floats2half2_rn(a2, a3);
    __syncthreads();
    // ---- MFMA phase: wave wv -> col tiles t0=2wv, t1=2wv+1 ----
    int wv = threadIdx.x >> 6;
    int l  = threadIdx.x & 63;
    int lg = l >> 4, lr = l & 15;
    f16x8 aA0 = *(const f16x8*)&a_h[lr * 72 + 0 * 32 + lg * 8];
    f16x8 aA1 = *(const f16x8*)&a_h[lr * 72 + 1 * 32 + lg * 8];
    int t0 = wv * 2, t1 = wv * 2 + 1;
    f16x8 b00 = wfrag[(t0 * 2 + 0) * 64 + l];
    f16x8 b01 = wfrag[(t0 * 2 + 1) * 64 + l];
    f16x8 b10 = wfrag[(t1 * 2 + 0) * 64 + l];
    f16x8 b11 = wfrag[(t1 * 2 + 1) * 64 + l];
    f32x4 acc0 = {0.f, 0.f, 0.f, 0.f}, acc1 = {0.f, 0.f, 0.f, 0.f};
    acc0 = __builtin_amdgcn_mfma_f32_16x16x32_f16(aA0, b00, acc0, 0, 0, 0);
    acc0 = __builtin_amdgcn_mfma_f32_16x16x32_f16(aA1, b01, acc0, 0, 0, 0);
    acc1 = __builtin_amdgcn_mfma_f32_16x16x32_f16(aA0, b10, acc1, 0, 0, 0);
    acc1 = __builtin_amdgcn_mfma_f32_16x16x32_f16(aA1, b11, acc1, 0, 0, 0);
    // ---- epilogue: D col = lane&15, row = (lane>>4)*4 + r (verified layout) ----
    int row0 = blockIdx.x * 16;
    int c0 = t0 * 16 + lr, c1 = t1 * 16 + lr;
    float bias0 = b1[c0], bias1 = b1[c1];
#pragma unroll
    for (int r = 0; r < 4; ++r) {
        int row = row0 + lg * 4 + r;
        XH[row * H + c0] = __float2half_rn(fmaxf(acc0[r] + bias0, 0.f));
        XH[row * H + c1] = __float2half_rn(fmaxf(acc1[r] + bias1, 0.f));
    }
}

// ---- gemm2 via MFMA: ZH[:, 0:48] = XH @ W2pad (cols 40..47 zero via pad);
//      cols 48..63 left unwritten (never consumed unmasked). 64 rows/block. ----
constexpr int X2S = 136;   // padded LDS stride (halves): 2-way conflict = free
__global__ __launch_bounds__(256) void gemm2(const __half* __restrict__ XH,
                                             const f16x8* __restrict__ w2frag,
                                             __half* __restrict__ ZH) {
    __shared__ _Float16 x_h[64 * X2S] __attribute__((aligned(16)));
    int row0 = blockIdx.x * 64;
    // stage XH raw fp16: 1024 chunks of 8 halves
#pragma unroll
    for (int i = 0; i < 4; ++i) {
        int idx = threadIdx.x + i * 256;
        int r = idx >> 4, q = idx & 15;
        int grow = row0 + r;
        if (grow >= N) grow = N - 1;
        *(f16x8*)&x_h[r * X2S + q * 8] = *(const f16x8*)&XH[grow * H + q * 8];
    }
    __syncthreads();
    int wv = threadIdx.x >> 6;            // wave -> rows wv*16..+15
    int l  = threadIdx.x & 63;
    int lg = l >> 4, lr = l & 15;
    f16x8 a[4];
#pragma unroll
    for (int kc = 0; kc < 4; ++kc)
        a[kc] = *(const f16x8*)&x_h[(wv * 16 + lr) * X2S + kc * 32 + lg * 8];
#pragma unroll
    for (int ct = 0; ct < 3; ++ct) {
        f32x4 acc = {0.f, 0.f, 0.f, 0.f};
#pragma unroll
        for (int kc = 0; kc < 4; ++kc)
            acc = __builtin_amdgcn_mfma_f32_16x16x32_f16(a[kc],
                      w2frag[(ct * 4 + kc) * 64 + l], acc, 0, 0, 0);
        int col = ct * 16 + lr;
#pragma unroll
        for (int r = 0; r < 4; ++r) {
            int row = row0 + wv * 16 + lg * 4 + r;
            if (row < N) ZH[row * 64 + col] = __float2half_rn(acc[r]);
        }
    }
}

// ---- out[node] = softmax(Z[node] + sum Z[src] + b2) (R15, unchanged) ----
__global__ __launch_bounds__(256) void gather2_softmax(const __half2* __restrict__ ZH,
                                                       const int* __restrict__ csr,
                                                       const int2* __restrict__ rd,
                                                       const float* __restrict__ b2,
                                                       float4* __restrict__ out) {
    int node = blockIdx.x * 16 + (threadIdx.x >> 4);
    int fl = threadIdx.x & 15;
    const float2* Z4 = (const float2*)ZH;     // row = 16 float2 = 128 B
    int2 rdv = rd[node];
    int rs = rdv.x, d = rdv.y;
    if (d == 0) rs = 0;
    int cl = (d > 0) ? d - 1 : 0;
    int dmax = d;
    dmax = max(dmax, __shfl_xor(dmax, 16));
    dmax = max(dmax, __shfl_xor(dmax, 32));
    float a0, a1, a2, a3;
    {   // self-loop init
        float2 raw = Z4[node * 16 + fl];
        const __half2* hp = (const __half2*)&raw;
        float2 v0 = __half22float2(hp[0]), v1 = __half22float2(hp[1]);
        a0 = v0.x; a1 = v0.y; a2 = v1.x; a3 = v1.y;
    }
    for (int j0 = 0; j0 < dmax; j0 += 8) {
        int k[8]; float w[8];
#pragma unroll
        for (int t = 0; t < 8; ++t) {
            int jj = j0 + t;
            bool ok = jj < d;
            w[t] = ok ? 1.f : 0.f;
            k[t] = csr[rs + (ok ? jj : cl)];
        }
#pragma unroll
        for (int t = 0; t < 8; ++t) {
            float2 raw = Z4[k[t] * 16 + fl];
            const __half2* hp = (const __half2*)&raw;
            float2 v0 = __half22float2(hp[0]), v1 = __half22float2(hp[1]);
            a0 = fmaf(w[t], v0.x, a0); a1 = fmaf(w[t], v0.y, a1);
            a2 = fmaf(w[t], v1.x, a2); a3 = fmaf(w[t], v1.y, a3);
        }
    }
    // softmax over the 40 real cols (lanes fl<10, cols 4fl..4fl+3)
    const float4* b4 = (const float4*)b2;
    bool real = fl < 10;
    float4 bb = b4[real ? fl : 9];
    float v0 = real ? a0 + bb.x : -INFINITY;
    float v1 = real ? a1 + bb.y : -INFINITY;
    float v2 = real ? a2 + bb.z : -INFINITY;
    float v3 = real ? a3 + bb.w : -INFINITY;
    float m = fmaxf(fmaxf(v0, v1), fmaxf(v2, v3));
#pragma unroll
    for (int off = 1; off < 16; off <<= 1) m = fmaxf(m, __shfl_xor(m, off));
    float e0 = __expf(v0 - m), e1 = __expf(v1 - m);   // -inf lanes -> exp = 0
    float e2 = __expf(v2 - m), e3 = __expf(v3 - m);
    float s = (e0 + e1) + (e2 + e3);
#pragma unroll
    for (int off = 1; off < 16; off <<= 1) s += __shfl_xor(s, off);
    float inv = 1.f / s;
    if (real)
        out[node * 10 + fl] = make_float4(e0 * inv, e1 * inv, e2 * inv, e3 * inv);
}

extern "C" void kernel_launch(void* const* d_in, const int* in_sizes, int n_in,
                              void* d_out, int out_size, void* d_ws, size_t ws_size,
                              hipStream_t stream) {
    const float* h   = (const float*)d_in[0];   // N*D
    const int*   adj = (const int*)  d_in[1];   // E*2
    const float* W1  = (const float*)d_in[2];   // D*H
    const float* b1  = (const float*)d_in[3];   // H
    const float* W2  = (const float*)d_in[4];   // H*C
    const float* b2  = (const float*)d_in[5];   // C
    float* out = (float*)d_out;                 // N*C fp32

    // workspace, NO aliasing:
    //   w1frag 16KB | w2frag 12KB | HH N*64 | XH N*128 | ZH N*64 | ints
    f16x8*  w1frag = (f16x8*)d_ws;                       // 1024 x 16 B
    f16x8*  w2frag = w1frag + 1024;                      // 768 x 16 B
    __half* HH = (__half*)(w2frag + 768);                // N*64 fp16
    __half* XH = HH + (size_t)N * 64;                    // N*128 fp16
    __half* ZH = XH + (size_t)N * H;                     // N*64 fp16
    int* partial   = (int*)(ZH + (size_t)N * 64);        // NHB*NBUCK2
    int* obase     = partial + NHB * NBUCK2;             // NBUCK2*NHB
    int* btot      = obase + NBUCK2 * NHB;               // 128
    int* staging   = btot + 128;                         // E
    int* csr       = staging + E;                        // E
    int2* rd       = (int2*)(csr + E);                   // N (row_start, deg)

    histo_conv<<<NHB, 256, 0, stream>>>((const int2*)adj, partial,
                                        (const float2*)h, (__half2*)HH,
                                        W1, W2, w1frag, w2frag);
    scan_pb   <<<NBUCK2, 1024, 0, stream>>>(partial, obase, btot);
    append_b  <<<NHB, 256, 0, stream>>>((const int2*)adj, btot, obase, staging);
    fill_b    <<<NBUCK2, 1024, 0, stream>>>(staging, btot, rd, csr);

    fused1         <<<N / 16, 256, 0, stream>>>((const __half2*)HH, csr, rd,
                                                w1frag, b1, XH);
    gemm2          <<<(N + 63) / 64, 256, 0, stream>>>(XH, w2frag, ZH);
    gather2_softmax<<<N / 16, 256, 0, stream>>>((const __half2*)ZH, csr, rd,
                                                b2, (float4*)out);
}

// Round 9
// 189.106 us; speedup vs baseline: 1.1810x; 1.0023x over previous
//
#include <hip/hip_runtime.h>
#include <hip/hip_fp16.h>
#include <math.h>

// GCN: out = softmax( S·relu((S·h)W1 + b1) · W2 + b2 ),  S = in-edge sum + self-loop.
// Round 19: R18 (best, 189.5us) + CSR build collapsed to SINGLE edge pass:
// fixed-capacity bucket staging (98 x 16384 ints) + per-block LDS aggregation +
// one global atomicAdd per (block,bucket). Deletes histo edge-pass, scan_pb, and
// the partial/obase/btot arrays (7 -> 6 launches). fill_b: window = b*16384 (no
// cross-bucket scan) and 1024-scan -> wave shfl_up scan (20 barriers -> 2).
// fused1 / gemm2 / gather2_softmax are UNCHANGED from R18.

constexpr int N = 100000;
constexpr int E = 1200000;
constexpr int D = 64;    // input dim
constexpr int H = 128;   // hidden
constexpr int C = 40;    // classes
constexpr int NBUCK2 = 98;                      // buckets of 1024 dst nodes
constexpr int EBLK   = 2048;                    // edges per append block
constexpr int NHB    = (E + EBLK - 1) / EBLK;   // 586 edge blocks
constexpr int SCAP   = 16384;                   // staging/csr capacity per bucket
constexpr int PREPB  = 1024;                    // prep grid

typedef _Float16 f16x8 __attribute__((ext_vector_type(8)));
typedef float    f32x4 __attribute__((ext_vector_type(4)));

// ---- prep: h->fp16 convert + W1/W2 fragment packs + gcnt zero ----
__global__ __launch_bounds__(256) void prep(const float2* __restrict__ hf,
                                            __half2* __restrict__ HH,
                                            const float* __restrict__ W1,
                                            const float* __restrict__ W2,
                                            f16x8* __restrict__ w1frag,
                                            f16x8* __restrict__ w2frag,
                                            int* __restrict__ gcnt) {
    if (blockIdx.x < 4) {                       // pack W1 -> 1024 frags
        int e = blockIdx.x * 256 + threadIdx.x;
        int l = e & 63, cf = e >> 6;            // cf = ct*2+f
        int f = cf & 1, ct = cf >> 1;
        int kbase = f * 32 + (l >> 4) * 8;
        int c = ct * 16 + (l & 15);
        f16x8 v;
#pragma unroll
        for (int r = 0; r < 8; ++r)
            v[r] = (_Float16)W1[(kbase + r) * H + c];
        w1frag[e] = v;
    } else if (blockIdx.x < 7) {                // pack W2 -> 768 frags (48-col pad)
        int e = (blockIdx.x - 4) * 256 + threadIdx.x;
        int l = e & 63, cf = e >> 6;            // cf = ct*4+kc
        int kc = cf & 3, ct = cf >> 2;
        int kbase = kc * 32 + (l >> 4) * 8;
        int c = ct * 16 + (l & 15);
        f16x8 v;
#pragma unroll
        for (int r = 0; r < 8; ++r)
            v[r] = (c < C) ? (_Float16)W2[(kbase + r) * C + c] : (_Float16)0.f;
        w2frag[e] = v;
    } else if (blockIdx.x == 7 && threadIdx.x < 128) {
        gcnt[threadIdx.x] = 0;
    }
    for (int i = blockIdx.x * 256 + threadIdx.x; i < N * 32; i += PREPB * 256) {
        float2 p = hf[i];
        HH[i] = __floats2half2_rn(p.x, p.y);
    }
}

// ---- single-pass append: LDS bucket count -> one global atomicAdd per
//      (block,bucket) -> scatter into fixed-capacity bucket windows ----
__global__ __launch_bounds__(256) void append_d(const int2* __restrict__ edges,
                                                int* __restrict__ gcnt,
                                                int* __restrict__ staging) {
    __shared__ int lcnt[NBUCK2], lbase[NBUCK2];
    int t = threadIdx.x;
    if (t < NBUCK2) lcnt[t] = 0;
    __syncthreads();
    int base = blockIdx.x * EBLK + t * 8;
    int2 ed[8]; int pos[8];
#pragma unroll
    for (int i = 0; i < 8; ++i) {
        int e = base + i;
        if (e < E) {
            ed[i] = edges[e];
            pos[i] = atomicAdd(&lcnt[ed[i].y >> 10], 1);   // LDS atomic
        }
    }
    __syncthreads();
    if (t < NBUCK2 && lcnt[t]) lbase[t] = atomicAdd(&gcnt[t], lcnt[t]);
    __syncthreads();
#pragma unroll
    for (int i = 0; i < 8; ++i) {
        int e = base + i;
        if (e < E) {
            int b = ed[i].y >> 10;
            int p = lbase[b] + pos[i];
            if (p < SCAP)                                   // never in practice
                staging[b * SCAP + p] = (ed[i].x << 10) | (ed[i].y & 1023);
        }
    }
}

// ---- per-bucket: LDS count -> wave-scan -> rd(row_start,deg), scatter csr ----
__global__ __launch_bounds__(1024) void fill_b(const int* __restrict__ staging,
                                               const int* __restrict__ gcnt,
                                               int2* __restrict__ rd,
                                               int* __restrict__ csr) {
    __shared__ int cnt[1024], cur[1024], wtot[16], wbase[16];
    int b = blockIdx.x, t = threadIdx.x;
    cnt[t] = 0;
    __syncthreads();
    int tot = gcnt[b];
    if (tot > SCAP) tot = SCAP;
    int lo = b * SCAP;
    for (int i = t; i < tot; i += 1024)
        atomicAdd(&cnt[staging[lo + i] & 1023], 1);
    __syncthreads();
    int v = cnt[t];
    int lane = t & 63, wid = t >> 6;
    int sv = v;                                  // inclusive wave scan
#pragma unroll
    for (int off = 1; off < 64; off <<= 1) {
        int x = __shfl_up(sv, off);
        if (lane >= off) sv += x;
    }
    if (lane == 63) wtot[wid] = sv;
    __syncthreads();
    if (t == 0) {
        int run = 0;
#pragma unroll
        for (int i = 0; i < 16; ++i) { wbase[i] = run; run += wtot[i]; }
    }
    __syncthreads();
    int ex = sv - v + wbase[wid];
    cur[t] = ex;
    int node = (b << 10) + t;
    if (node < N) rd[node] = make_int2(lo + ex, v);
    __syncthreads();
    for (int i = t; i < tot; i += 1024) {
        int w = staging[lo + i];
        int p = atomicAdd(&cur[w & 1023], 1);
        csr[lo + p] = w >> 10;
    }
}

// ---- FUSED layer 1 (R18, unchanged): gather (4 nodes/wave, 16 lanes/node,
//      batch-8) -> fp16 LDS a_h[16][72], then MFMA 16x16x32_f16 ----
__global__ __launch_bounds__(256) void fused1(const __half2* __restrict__ HH,
                                              const int* __restrict__ csr,
                                              const int2* __restrict__ rd,
                                              const f16x8* __restrict__ wfrag,
                                              const float* __restrict__ b1,
                                              __half* __restrict__ XH) {
    __shared__ _Float16 a_h[16 * 72] __attribute__((aligned(16)));
    int nl = threadIdx.x >> 4;                 // node-local 0..15
    int fl = threadIdx.x & 15;
    int node = blockIdx.x * 16 + nl;
    const float2* H4 = (const float2*)HH;      // row = 16 float2 = 128 B
    int2 rdv = rd[node];
    int rs = rdv.x, d = rdv.y;
    if (d == 0) rs = 0;                        // safe dummy window
    int cl = (d > 0) ? d - 1 : 0;
    int dmax = d;                              // wave-uniform loop bound
    dmax = max(dmax, __shfl_xor(dmax, 16));
    dmax = max(dmax, __shfl_xor(dmax, 32));
    float a0, a1, a2, a3;
    {   // self-loop init
        float2 raw = H4[node * 16 + fl];
        const __half2* hp = (const __half2*)&raw;
        float2 v0 = __half22float2(hp[0]), v1 = __half22float2(hp[1]);
        a0 = v0.x; a1 = v0.y; a2 = v1.x; a3 = v1.y;
    }
    for (int j0 = 0; j0 < dmax; j0 += 8) {     // 8 rows in flight per node
        int k[8]; float w[8];
#pragma unroll
        for (int t = 0; t < 8; ++t) {
            int jj = j0 + t;
            bool ok = jj < d;
            w[t] = ok ? 1.f : 0.f;
            k[t] = csr[rs + (ok ? jj : cl)];
        }
#pragma unroll
        for (int t = 0; t < 8; ++t) {
            float2 raw = H4[k[t] * 16 + fl];
            const __half2* hp = (const __half2*)&raw;
            float2 v0 = __half22float2(hp[0]), v1 = __half22float2(hp[1]);
            a0 = fmaf(w[t], v0.x, a0); a1 = fmaf(w[t], v0.y, a1);
            a2 = fmaf(w[t], v1.x, a2); a3 = fmaf(w[t], v1.y, a3);
        }
    }
    *(__half2*)&a_h[nl * 72 + fl * 4]     = __floats2half2_rn(a0, a1);
    *(__half2*)&a_h[nl * 72 + fl * 4 + 2] = __floats2half2_rn(a2, a3);
    __syncthreads();
    // ---- MFMA phase: wave wv -> col tiles t0=2wv, t1=2wv+1 ----
    int wv = threadIdx.x >> 6;
    int l  = threadIdx.x & 63;
    int lg = l >> 4, lr = l & 15;
    f16x8 aA0 = *(const f16x8*)&a_h[lr * 72 + 0 * 32 + lg * 8];
    f16x8 aA1 = *(const f16x8*)&a_h[lr * 72 + 1 * 32 + lg * 8];
    int t0 = wv * 2, t1 = wv * 2 + 1;
    f16x8 b00 = wfrag[(t0 * 2 + 0) * 64 + l];
    f16x8 b01 = wfrag[(t0 * 2 + 1) * 64 + l];
    f16x8 b10 = wfrag[(t1 * 2 + 0) * 64 + l];
    f16x8 b11 = wfrag[(t1 * 2 + 1) * 64 + l];
    f32x4 acc0 = {0.f, 0.f, 0.f, 0.f}, acc1 = {0.f, 0.f, 0.f, 0.f};
    acc0 = __builtin_amdgcn_mfma_f32_16x16x32_f16(aA0, b00, acc0, 0, 0, 0);
    acc0 = __builtin_amdgcn_mfma_f32_16x16x32_f16(aA1, b01, acc0, 0, 0, 0);
    acc1 = __builtin_amdgcn_mfma_f32_16x16x32_f16(aA0, b10, acc1, 0, 0, 0);
    acc1 = __builtin_amdgcn_mfma_f32_16x16x32_f16(aA1, b11, acc1, 0, 0, 0);
    // ---- epilogue: D col = lane&15, row = (lane>>4)*4 + r (verified layout) ----
    int row0 = blockIdx.x * 16;
    int c0 = t0 * 16 + lr, c1 = t1 * 16 + lr;
    float bias0 = b1[c0], bias1 = b1[c1];
#pragma unroll
    for (int r = 0; r < 4; ++r) {
        int row = row0 + lg * 4 + r;
        XH[row * H + c0] = __float2half_rn(fmaxf(acc0[r] + bias0, 0.f));
        XH[row * H + c1] = __float2half_rn(fmaxf(acc1[r] + bias1, 0.f));
    }
}

// ---- gemm2 via MFMA (R18, unchanged): ZH[:,0:48] = XH @ W2pad; 64 rows/block ----
constexpr int X2S = 136;   // padded LDS stride (halves): 2-way conflict = free
__global__ __launch_bounds__(256) void gemm2(const __half* __restrict__ XH,
                                             const f16x8* __restrict__ w2frag,
                                             __half* __restrict__ ZH) {
    __shared__ _Float16 x_h[64 * X2S] __attribute__((aligned(16)));
    int row0 = blockIdx.x * 64;
    // stage XH raw fp16: 1024 chunks of 8 halves
#pragma unroll
    for (int i = 0; i < 4; ++i) {
        int idx = threadIdx.x + i * 256;
        int r = idx >> 4, q = idx & 15;
        int grow = row0 + r;
        if (grow >= N) grow = N - 1;
        *(f16x8*)&x_h[r * X2S + q * 8] = *(const f16x8*)&XH[grow * H + q * 8];
    }
    __syncthreads();
    int wv = threadIdx.x >> 6;            // wave -> rows wv*16..+15
    int l  = threadIdx.x & 63;
    int lg = l >> 4, lr = l & 15;
    f16x8 a[4];
#pragma unroll
    for (int kc = 0; kc < 4; ++kc)
        a[kc] = *(const f16x8*)&x_h[(wv * 16 + lr) * X2S + kc * 32 + lg * 8];
#pragma unroll
    for (int ct = 0; ct < 3; ++ct) {
        f32x4 acc = {0.f, 0.f, 0.f, 0.f};
#pragma unroll
        for (int kc = 0; kc < 4; ++kc)
            acc = __builtin_amdgcn_mfma_f32_16x16x32_f16(a[kc],
                      w2frag[(ct * 4 + kc) * 64 + l], acc, 0, 0, 0);
        int col = ct * 16 + lr;
#pragma unroll
        for (int r = 0; r < 4; ++r) {
            int row = row0 + wv * 16 + lg * 4 + r;
            if (row < N) ZH[row * 64 + col] = __float2half_rn(acc[r]);
        }
    }
}

// ---- out[node] = softmax(Z[node] + sum Z[src] + b2) (R18, unchanged) ----
__global__ __launch_bounds__(256) void gather2_softmax(const __half2* __restrict__ ZH,
                                                       const int* __restrict__ csr,
                                                       const int2* __restrict__ rd,
                                                       const float* __restrict__ b2,
                                                       float4* __restrict__ out) {
    int node = blockIdx.x * 16 + (threadIdx.x >> 4);
    int fl = threadIdx.x & 15;
    const float2* Z4 = (const float2*)ZH;     // row = 16 float2 = 128 B
    int2 rdv = rd[node];
    int rs = rdv.x, d = rdv.y;
    if (d == 0) rs = 0;
    int cl = (d > 0) ? d - 1 : 0;
    int dmax = d;
    dmax = max(dmax, __shfl_xor(dmax, 16));
    dmax = max(dmax, __shfl_xor(dmax, 32));
    float a0, a1, a2, a3;
    {   // self-loop init
        float2 raw = Z4[node * 16 + fl];
        const __half2* hp = (const __half2*)&raw;
        float2 v0 = __half22float2(hp[0]), v1 = __half22float2(hp[1]);
        a0 = v0.x; a1 = v0.y; a2 = v1.x; a3 = v1.y;
    }
    for (int j0 = 0; j0 < dmax; j0 += 8) {
        int k[8]; float w[8];
#pragma unroll
        for (int t = 0; t < 8; ++t) {
            int jj = j0 + t;
            bool ok = jj < d;
            w[t] = ok ? 1.f : 0.f;
            k[t] = csr[rs + (ok ? jj : cl)];
        }
#pragma unroll
        for (int t = 0; t < 8; ++t) {
            float2 raw = Z4[k[t] * 16 + fl];
            const __half2* hp = (const __half2*)&raw;
            float2 v0 = __half22float2(hp[0]), v1 = __half22float2(hp[1]);
            a0 = fmaf(w[t], v0.x, a0); a1 = fmaf(w[t], v0.y, a1);
            a2 = fmaf(w[t], v1.x, a2); a3 = fmaf(w[t], v1.y, a3);
        }
    }
    // softmax over the 40 real cols (lanes fl<10, cols 4fl..4fl+3)
    const float4* b4 = (const float4*)b2;
    bool real = fl < 10;
    float4 bb = b4[real ? fl : 9];
    float v0 = real ? a0 + bb.x : -INFINITY;
    float v1 = real ? a1 + bb.y : -INFINITY;
    float v2 = real ? a2 + bb.z : -INFINITY;
    float v3 = real ? a3 + bb.w : -INFINITY;
    float m = fmaxf(fmaxf(v0, v1), fmaxf(v2, v3));
#pragma unroll
    for (int off = 1; off < 16; off <<= 1) m = fmaxf(m, __shfl_xor(m, off));
    float e0 = __expf(v0 - m), e1 = __expf(v1 - m);   // -inf lanes -> exp = 0
    float e2 = __expf(v2 - m), e3 = __expf(v3 - m);
    float s = (e0 + e1) + (e2 + e3);
#pragma unroll
    for (int off = 1; off < 16; off <<= 1) s += __shfl_xor(s, off);
    float inv = 1.f / s;
    if (real)
        out[node * 10 + fl] = make_float4(e0 * inv, e1 * inv, e2 * inv, e3 * inv);
}

extern "C" void kernel_launch(void* const* d_in, const int* in_sizes, int n_in,
                              void* d_out, int out_size, void* d_ws, size_t ws_size,
                              hipStream_t stream) {
    const float* h   = (const float*)d_in[0];   // N*D
    const int*   adj = (const int*)  d_in[1];   // E*2
    const float* W1  = (const float*)d_in[2];   // D*H
    const float* b1  = (const float*)d_in[3];   // H
    const float* W2  = (const float*)d_in[4];   // H*C
    const float* b2  = (const float*)d_in[5];   // C
    float* out = (float*)d_out;                 // N*C fp32

    // workspace (~64.5 MB), NO aliasing:
    //   w1frag 16KB | w2frag 12KB | HH N*64 | XH N*128 | ZH N*64 |
    //   gcnt 128 | staging 98*16384 | csr 98*16384 | rd N int2
    f16x8*  w1frag = (f16x8*)d_ws;                       // 1024 x 16 B
    f16x8*  w2frag = w1frag + 1024;                      // 768 x 16 B
    __half* HH = (__half*)(w2frag + 768);                // N*64 fp16
    __half* XH = HH + (size_t)N * 64;                    // N*128 fp16
    __half* ZH = XH + (size_t)N * H;                     // N*64 fp16
    int* gcnt    = (int*)(ZH + (size_t)N * 64);          // 128
    int* staging = gcnt + 128;                           // NBUCK2*SCAP
    int* csr     = staging + NBUCK2 * SCAP;              // NBUCK2*SCAP
    int2* rd     = (int2*)(csr + NBUCK2 * SCAP);         // N (row_start, deg)

    prep     <<<PREPB, 256, 0, stream>>>((const float2*)h, (__half2*)HH,
                                         W1, W2, w1frag, w2frag, gcnt);
    append_d <<<NHB, 256, 0, stream>>>((const int2*)adj, gcnt, staging);
    fill_b   <<<NBUCK2, 1024, 0, stream>>>(staging, gcnt, rd, csr);

    fused1         <<<N / 16, 256, 0, stream>>>((const __half2*)HH, csr, rd,
                                                w1frag, b1, XH);
    gemm2          <<<(N + 63) / 64, 256, 0, stream>>>(XH, w2frag, ZH);
    gather2_softmax<<<N / 16, 256, 0, stream>>>((const __half2*)ZH, csr, rd,
                                                b2, (float4*)out);
}